// Round 9
// baseline (288.775 us; speedup 1.0000x reference)
//
#include <hip/hip_runtime.h>
#include <math.h>

#define G     1000
#define B     32
#define NC    2048
#define NT    2048
#define BN    (B * NT)
#define LOG2E 1.4426950408889634f
#define LN2PI 1.8378770664093453f   // ln(2*pi)

// Attribution round: internal idempotent repeats to surface per-kernel
// durations + counters in rocprof top-5 (fills are 38-39us; these run longer).
#define SREP 9
#define CREP 9
#define PREP 12

#if __has_builtin(__builtin_amdgcn_exp2f)
#define EXP2F(x) __builtin_amdgcn_exp2f(x)
#else
#define EXP2F(x) exp2f(x)
#endif

// ---------------------------------------------------------------------------
// Kernel A v4 (body frozen; x9 internal reps this round)
// ---------------------------------------------------------------------------
__global__ __launch_bounds__(512) void k_smooth(
    const float* __restrict__ xc, const float* __restrict__ yc,
    const float* __restrict__ ls_x, float* __restrict__ h,
    float* __restrict__ loss_slot) {
  __shared__ float sxy[NC * 2];           // {s*x_n, y_n} interleaved, 16KB
  __shared__ float pA0[512], pA1[512], pB0[512], pB1[512];

  int tid = threadIdx.x;
  int b = blockIdx.y, tile = blockIdx.x;

  #pragma unroll 1
  for (int rep = 0; rep < SREP; ++rep) {
    asm volatile("" ::: "memory");
    if (blockIdx.x == 0 && blockIdx.y == 0 && tid == 0) *loss_slot = 0.f;

    float ls = ls_x[0];
    float s  = sqrtf(0.5f * LOG2E) / ls;  // w = exp2(-(s*t - s*x)^2)

    const float* xb = xc + b * NC;
    const float* yb = yc + b * NC;
    for (int n = tid; n < NC; n += 512) {
      sxy[2 * n]     = s * xb[n];
      sxy[2 * n + 1] = yb[n];
    }
    __syncthreads();

    int lane = tid & 63, wv = tid >> 6;
    int ga = tile * 128 + lane;
    float step = s * (4.4f / 999.f);
    float tga = s * -2.2f + step * (float)ga;
    float tgb = tga + step * 64.f;

    float a0 = 0.f, a1 = 0.f, b0 = 0.f, b1 = 0.f;
    const float4* p = ((const float4*)sxy) + wv * (NC / 16);
    #pragma unroll 4
    for (int i = 0; i < NC / 16; ++i) {
      float4 v = p[i];
      float d, w;
      d = tga - v.x; w = EXP2F(-(d * d)); a0 += w; a1 = fmaf(w, v.y, a1);
      d = tgb - v.x; w = EXP2F(-(d * d)); b0 += w; b1 = fmaf(w, v.y, b1);
      d = tga - v.z; w = EXP2F(-(d * d)); a0 += w; a1 = fmaf(w, v.w, a1);
      d = tgb - v.z; w = EXP2F(-(d * d)); b0 += w; b1 = fmaf(w, v.w, b1);
    }
    pA0[tid] = a0; pA1[tid] = a1; pB0[tid] = b0; pB1[tid] = b1;
    __syncthreads();

    if (tid < 128) {
      int which = tid >> 6, l = tid & 63;
      int g = tile * 128 + which * 64 + l;
      if (g < G) {
        const float* q0 = which ? pB0 : pA0;
        const float* q1 = which ? pB1 : pA1;
        float d0 = 0.f, d1 = 0.f;
        #pragma unroll
        for (int k = 0; k < 8; ++k) { d0 += q0[l + 64 * k]; d1 += q1[l + 64 * k]; }
        h[(b * 2 + 0) * G + g] = d0;
        h[(b * 2 + 1) * G + g] = d1 / (d0 + 1e-8f);
      }
    }
    __syncthreads();
  }
}

// ---------------------------------------------------------------------------
// Kernel B v5 (body frozen; x9 internal reps this round)
// ---------------------------------------------------------------------------
#define TILE  48
#define NTILE 21   // 21*48 = 1008 >= 1000
#define CSTR  68

template <int CIN, int COUT, int WSTR, int NPASS>
__device__ __forceinline__ void conv_layer5(
    const float* __restrict__ in, float* __restrict__ out,
    const float* __restrict__ wt, const float* __restrict__ bias, int tid) {
  #pragma unroll
  for (int pass = 0; pass < NPASS; ++pass) {
    int idx = tid + pass * 256;
    int oc  = idx % COUT;
    int i0  = (idx / COUT) * 4;
    float acc[4];
    float bb = bias[oc];
    #pragma unroll
    for (int p = 0; p < 4; ++p) acc[p] = bb;
    for (int ic = 0; ic < CIN; ++ic) {
      const float* ip = in + ic * CSTR + i0;
      float4 va = *(const float4*)ip;
      float4 vb = *(const float4*)(ip + 4);
      float v[8] = {va.x, va.y, va.z, va.w, vb.x, vb.y, vb.z, vb.w};
      const float* wp = wt + oc * WSTR + ic * 5;
      float w[5];
      #pragma unroll
      for (int k = 0; k < 5; ++k) w[k] = wp[k];
      #pragma unroll
      for (int p = 0; p < 4; ++p)
        #pragma unroll
        for (int k = 0; k < 5; ++k)
          acc[p] = fmaf(v[p + k], w[k], acc[p]);
    }
    float* op = out + oc * CSTR + i0 + 2;
    *(float2*)op       = make_float2(fmaxf(acc[0], 0.f), fmaxf(acc[1], 0.f));
    *(float2*)(op + 2) = make_float2(fmaxf(acc[2], 0.f), fmaxf(acc[3], 0.f));
  }
}

__global__ __launch_bounds__(256, 4) void k_conv(
    const float* __restrict__ h,
    const float* __restrict__ W1, const float* __restrict__ Bs1,
    const float* __restrict__ W2, const float* __restrict__ Bs2,
    const float* __restrict__ W3, const float* __restrict__ Bs3,
    const float* __restrict__ W4, const float* __restrict__ Bs4,
    float* __restrict__ yg) {
  __shared__ __align__(16) float bufA[32 * CSTR], bufB[32 * CSTR];
  __shared__ float wt1[176], wt2[2592], wt3[2576], wt4[162];
  __shared__ float sB1[16], sB2[32], sB3[16], sB4[2];

  int tid  = threadIdx.x;
  int tile = blockIdx.x, b = blockIdx.y;
  int ts   = tile * TILE;

  #pragma unroll 1
  for (int rep = 0; rep < CREP; ++rep) {
    asm volatile("" ::: "memory");
    for (int i = tid; i < 160;  i += 256) wt1[(i / 10)  * 11  + i % 10]  = W1[i];
    for (int i = tid; i < 2560; i += 256) wt2[(i / 80)  * 81  + i % 80]  = W2[i];
    for (int i = tid; i < 2560; i += 256) wt3[(i / 160) * 161 + i % 160] = W3[i];
    for (int i = tid; i < 160;  i += 256) wt4[(i / 80)  * 81  + i % 80]  = W4[i];
    if (tid < 16)       sB1[tid]      = Bs1[tid];
    else if (tid < 48)  sB2[tid - 16] = Bs2[tid - 16];
    else if (tid < 64)  sB3[tid - 48] = Bs3[tid - 48];
    else if (tid < 66)  sB4[tid - 64] = Bs4[tid - 64];

    for (int i = tid; i < 2 * CSTR; i += 256) {
      int c = i >= CSTR, col = i - c * CSTR;
      int g = ts + col - 10;
      bufA[c * CSTR + col] = (g >= 0 && g < G) ? h[(b * 2 + c) * G + g] : 0.f;
    }
    __syncthreads();

    conv_layer5<2, 16, 11, 1>(bufA, bufB, wt1, sB1, tid);
    __syncthreads();
    conv_layer5<16, 32, 81, 2>(bufB, bufA, wt2, sB2, tid);
    __syncthreads();
    conv_layer5<32, 16, 161, 1>(bufA, bufB, wt3, sB3, tid);
    __syncthreads();

    if (tid < 96) {
      int oc = tid >= 48;
      int j  = tid - oc * 48;
      int i  = 10 + j;
      float sacc = sB4[oc];
      #pragma unroll
      for (int ic = 0; ic < 16; ++ic) {
        const float* ip = bufB + ic * CSTR + i - 2;
        #pragma unroll
        for (int k = 0; k < 5; ++k)
          sacc = fmaf(ip[k], wt4[oc * 81 + ic * 5 + k], sacc);
      }
      int gp = ts + j;
      if (gp < G) {
        if (oc == 0) {
          yg[(b * 2 + 0) * G + gp] = sacc;
        } else {
          float sp_ = fmaxf(sacc, 0.f) + log1pf(__expf(-fabsf(sacc)));
          yg[(b * 2 + 1) * G + gp] = sp_;
        }
      }
    }
    __syncthreads();
  }
}

// ---------------------------------------------------------------------------
// Kernel C v5 (body frozen; x12 internal reps; loss atomic on last rep only)
// ---------------------------------------------------------------------------
__global__ __launch_bounds__(512) void k_pred(
    const float* __restrict__ xt, const float* __restrict__ yt,
    const float* __restrict__ ls_rho, const float* __restrict__ yg,
    float* __restrict__ out) {
  __shared__ float2 sp[G];                // {y0_g, y1_g}, 8KB
  __shared__ float pA0[512], pA1[512], pB0[512], pB1[512];
  __shared__ float red[8];

  int tid = threadIdx.x;
  int b = blockIdx.y, tile = blockIdx.x;

  #pragma unroll 1
  for (int rep = 0; rep < PREP; ++rep) {
    asm volatile("" ::: "memory");
    float ls = ls_rho[0];
    float s  = sqrtf(0.5f * LOG2E) / ls;
    float dl = s * (4.4f / 999.f);

    const float* y0 = yg + (b * 2 + 0) * G;
    const float* y1 = yg + (b * 2 + 1) * G;
    for (int g = tid; g < G; g += 512) sp[g] = make_float2(y0[g], y1[g]);
    __syncthreads();

    int lane = tid & 63, wv = tid >> 6;
    int ta = tile * 128 + lane;
    float ua = s * xt[b * NT + ta];
    float ub = s * xt[b * NT + ta + 64];
    float base = 2.2f * s - dl * (float)(wv * 125);
    float aa = ua + base, ab = ub + base;
    float Wa = EXP2F(64.f - aa * aa), qa = EXP2F(dl * (aa + aa) - dl * dl);
    float Wb = EXP2F(64.f - ab * ab), qb = EXP2F(dl * (ab + ab) - dl * dl);
    float r  = EXP2F(-2.f * dl * dl);

    float muA = 0.f, sgA = 0.f, muB = 0.f, sgB = 0.f;
    const float2* p = sp + wv * 125;
    #pragma unroll 5
    for (int i = 0; i < 125; ++i) {
      float2 v = p[i];
      muA = fmaf(Wa, v.x, muA); sgA = fmaf(Wa, v.y, sgA); Wa *= qa; qa *= r;
      muB = fmaf(Wb, v.x, muB); sgB = fmaf(Wb, v.y, sgB); Wb *= qb; qb *= r;
    }
    pA0[tid] = muA; pA1[tid] = sgA; pB0[tid] = muB; pB1[tid] = sgB;
    __syncthreads();

    float lp = 0.f;
    if (tid < 128) {
      int which = tid >> 6, l = tid & 63;
      int t = tile * 128 + which * 64 + l;
      const float* q0 = which ? pB0 : pA0;
      const float* q1 = which ? pB1 : pA1;
      float mu = 0.f, sg = 0.f;
      #pragma unroll
      for (int k = 0; k < 8; ++k) { mu += q0[l + 64 * k]; sg += q1[l + 64 * k]; }
      mu *= 0x1p-64f;
      sg *= 0x1p-64f;
      out[b * NT + t]      = mu;
      out[BN + b * NT + t] = sg;
      float z = (yt[b * NT + t] - mu) / sg;
      lp = -0.5f * z * z - __logf(sg) - 0.5f * LN2PI;
    }
    #pragma unroll
    for (int m = 32; m; m >>= 1) lp += __shfl_xor(lp, m);
    if ((tid & 63) == 0) red[tid >> 6] = lp;
    __syncthreads();
    if (tid == 0 && rep == PREP - 1) {
      float tot = 0.f;
      #pragma unroll
      for (int i = 0; i < 8; ++i) tot += red[i];
      atomicAdd(out + 2 * BN, -tot * (1.f / (float)NT));
    }
    __syncthreads();
  }
}

extern "C" void kernel_launch(void* const* d_in, const int* in_sizes, int n_in,
                              void* d_out, int out_size, void* d_ws, size_t ws_size,
                              hipStream_t stream) {
  const float* xc  = (const float*)d_in[0];
  const float* yc  = (const float*)d_in[1];
  const float* xt  = (const float*)d_in[2];
  const float* yt  = (const float*)d_in[3];
  const float* lsx = (const float*)d_in[4];
  const float* lsr = (const float*)d_in[5];
  const float* W1  = (const float*)d_in[6];  const float* b1 = (const float*)d_in[7];
  const float* W2  = (const float*)d_in[8];  const float* b2 = (const float*)d_in[9];
  const float* W3  = (const float*)d_in[10]; const float* b3 = (const float*)d_in[11];
  const float* W4  = (const float*)d_in[12]; const float* b4 = (const float*)d_in[13];

  float* out = (float*)d_out;
  float* h   = (float*)d_ws;        // B*2*G
  float* yg  = h + B * 2 * G;       // B*2*G

  k_smooth<<<dim3(8, B), 512, 0, stream>>>(xc, yc, lsx, h, out + 2 * BN);
  k_conv<<<dim3(NTILE, B), 256, 0, stream>>>(h, W1, b1, W2, b2, W3, b3, W4, b4, yg);
  k_pred<<<dim3(16, B), 512, 0, stream>>>(xt, yt, lsr, yg, out);
}

// Round 10
// 43.916 us; speedup vs baseline: 6.5757x; 6.5757x over previous
//
#include <hip/hip_runtime.h>
#include <math.h>

#define G     1000
#define B     32
#define NC    2048
#define NT    2048
#define BN    (B * NT)
#define LOG2E 1.4426950408889634f
#define LN2PI 1.8378770664093453f   // ln(2*pi)

#if __has_builtin(__builtin_amdgcn_exp2f)
#define EXP2F(x) __builtin_amdgcn_exp2f(x)
#else
#define EXP2F(x) exp2f(x)
#endif

// ---------------------------------------------------------------------------
// Kernel A v4 (frozen — trans-bound at ~10us floor: 65.5M v_exp_f32).
// grid (8, B), block 512 = 8 n-slices x 64 lanes; lane owns 2 g.
// ---------------------------------------------------------------------------
__global__ __launch_bounds__(512) void k_smooth(
    const float* __restrict__ xc, const float* __restrict__ yc,
    const float* __restrict__ ls_x, float* __restrict__ h,
    float* __restrict__ loss_slot) {
  __shared__ float sxy[NC * 2];
  __shared__ float pA0[512], pA1[512], pB0[512], pB1[512];
  if (blockIdx.x == 0 && blockIdx.y == 0 && threadIdx.x == 0) *loss_slot = 0.f;

  int tid = threadIdx.x;
  int b = blockIdx.y, tile = blockIdx.x;
  float ls = ls_x[0];
  float s  = sqrtf(0.5f * LOG2E) / ls;

  const float* xb = xc + b * NC;
  const float* yb = yc + b * NC;
  for (int n = tid; n < NC; n += 512) {
    sxy[2 * n]     = s * xb[n];
    sxy[2 * n + 1] = yb[n];
  }
  __syncthreads();

  int lane = tid & 63, wv = tid >> 6;
  int ga = tile * 128 + lane;
  float step = s * (4.4f / 999.f);
  float tga = s * -2.2f + step * (float)ga;
  float tgb = tga + step * 64.f;

  float a0 = 0.f, a1 = 0.f, b0 = 0.f, b1 = 0.f;
  const float4* p = ((const float4*)sxy) + wv * (NC / 16);
  #pragma unroll 4
  for (int i = 0; i < NC / 16; ++i) {
    float4 v = p[i];
    float d, w;
    d = tga - v.x; w = EXP2F(-(d * d)); a0 += w; a1 = fmaf(w, v.y, a1);
    d = tgb - v.x; w = EXP2F(-(d * d)); b0 += w; b1 = fmaf(w, v.y, b1);
    d = tga - v.z; w = EXP2F(-(d * d)); a0 += w; a1 = fmaf(w, v.w, a1);
    d = tgb - v.z; w = EXP2F(-(d * d)); b0 += w; b1 = fmaf(w, v.w, b1);
  }
  pA0[tid] = a0; pA1[tid] = a1; pB0[tid] = b0; pB1[tid] = b1;
  __syncthreads();

  if (tid < 128) {
    int which = tid >> 6, l = tid & 63;
    int g = tile * 128 + which * 64 + l;
    if (g < G) {
      const float* q0 = which ? pB0 : pA0;
      const float* q1 = which ? pB1 : pA1;
      float d0 = 0.f, d1 = 0.f;
      #pragma unroll
      for (int k = 0; k < 8; ++k) { d0 += q0[l + 64 * k]; d1 += q1[l + 64 * k]; }
      h[(b * 2 + 0) * G + g] = d0;
      h[(b * 2 + 1) * G + g] = d1 / (d0 + 1e-8f);
    }
  }
}

// ---------------------------------------------------------------------------
// Kernel B v6: DS-instruction diet. POS=8 (NG=3), weights packed as float4
// {w0..3} at odd f4-stride (17/33 -> conflict-free) + separate w4 scalar
// array. Per-ic DS: 3 data-b128 + 1 w-b128 + 1 w-b32 = 5 instr for 8 outputs
// (was 7 for 4). TILE=48, grid (21 x B) = 672 blocks.
// Valid-region chain (CSTR=68, stage g in [ts-10, ts+58)):
//   L1 writes [2,66); L2 garbage cols [0,4)u[64,68); L3 clean [6,62);
//   L4 reads [8,60) subset of clean ✓ outputs g = ts + [0,48).
// ---------------------------------------------------------------------------
#define TILE  48
#define NTILE 21   // 21*48 = 1008 >= 1000
#define CSTR  68

template <int CIN, int COUT, int S4>
__device__ __forceinline__ void conv8(
    const float* __restrict__ in, float* __restrict__ out,
    const float4* __restrict__ wf4, const float* __restrict__ w4p,
    const float* __restrict__ bias, int tid) {
  if (tid < COUT * 8) {
    int oc = tid % COUT;
    int i0 = (tid / COUT) * 8;            // reads [i0,i0+12), writes [i0+2,i0+10)
    float acc[8];
    float bb = bias[oc];
    #pragma unroll
    for (int p = 0; p < 8; ++p) acc[p] = bb;
    for (int ic = 0; ic < CIN; ++ic) {
      const float4* ip = (const float4*)(in + ic * CSTR + i0);
      float4 A = ip[0], Bv = ip[1], C = ip[2];
      float v[12] = {A.x, A.y, A.z, A.w, Bv.x, Bv.y, Bv.z, Bv.w, C.x, C.y, C.z, C.w};
      float4 w = wf4[oc * S4 + ic];
      float w4v = w4p[ic * COUT + oc];
      #pragma unroll
      for (int p = 0; p < 8; ++p)
        acc[p] = fmaf(v[p], w.x, fmaf(v[p+1], w.y, fmaf(v[p+2], w.z,
                 fmaf(v[p+3], w.w, fmaf(v[p+4], w4v, acc[p])))));
    }
    float* op = out + oc * CSTR + i0 + 2;
    #pragma unroll
    for (int j = 0; j < 4; ++j)
      *(float2*)(op + 2 * j) = make_float2(fmaxf(acc[2*j], 0.f), fmaxf(acc[2*j+1], 0.f));
  }
}

__global__ __launch_bounds__(256, 2) void k_conv(
    const float* __restrict__ h,
    const float* __restrict__ W1, const float* __restrict__ Bs1,
    const float* __restrict__ W2, const float* __restrict__ Bs2,
    const float* __restrict__ W3, const float* __restrict__ Bs3,
    const float* __restrict__ W4, const float* __restrict__ Bs4,
    float* __restrict__ yg) {
  __shared__ __align__(16) float bufA[32 * CSTR], bufB[32 * CSTR];
  __shared__ float4 wf1[16 * 3], wf2[32 * 17], wf3[16 * 33];
  __shared__ float  w41[2 * 16], w42[16 * 32], w43[32 * 16];
  __shared__ float  wt4[162];
  __shared__ float  sB1[16], sB2[32], sB3[16], sB4[2];

  int tid  = threadIdx.x;
  int tile = blockIdx.x, b = blockIdx.y;
  int ts   = tile * TILE;

  // ---- weight staging: packed f4 {w0..3} + scalar w4 ----
  if (tid < 32) {                         // L1: oc<16, ic<2
    int oc = tid >> 1, ic = tid & 1, a = oc * 10 + ic * 5;
    wf1[oc * 3 + ic] = make_float4(W1[a], W1[a+1], W1[a+2], W1[a+3]);
    w41[ic * 16 + oc] = W1[a + 4];
  }
  for (int pr = tid; pr < 512; pr += 256) {   // L2: oc<32, ic<16
    int oc = pr >> 4, ic = pr & 15, a = oc * 80 + ic * 5;
    wf2[oc * 17 + ic] = make_float4(W2[a], W2[a+1], W2[a+2], W2[a+3]);
    w42[ic * 32 + oc] = W2[a + 4];
  }
  for (int pr = tid; pr < 512; pr += 256) {   // L3: oc<16, ic<32
    int oc = pr >> 5, ic = pr & 31, a = oc * 160 + ic * 5;
    wf3[oc * 33 + ic] = make_float4(W3[a], W3[a+1], W3[a+2], W3[a+3]);
    w43[ic * 16 + oc] = W3[a + 4];
  }
  for (int i = tid; i < 160; i += 256) wt4[(i / 80) * 81 + i % 80] = W4[i];
  if (tid < 16)       sB1[tid]      = Bs1[tid];
  else if (tid < 48)  sB2[tid - 16] = Bs2[tid - 16];
  else if (tid < 64)  sB3[tid - 48] = Bs3[tid - 48];
  else if (tid < 66)  sB4[tid - 64] = Bs4[tid - 64];

  // ---- stage input: col i in [0,68) <-> global g = ts + i - 10 ----
  for (int i = tid; i < 2 * CSTR; i += 256) {
    int c = i >= CSTR, col = i - c * CSTR;
    int g = ts + col - 10;
    bufA[c * CSTR + col] = (g >= 0 && g < G) ? h[(b * 2 + c) * G + g] : 0.f;
  }
  __syncthreads();

  conv8<2, 16, 3>(bufA, bufB, wf1, w41, sB1, tid);
  __syncthreads();
  conv8<16, 32, 17>(bufB, bufA, wf2, w42, sB2, tid);
  __syncthreads();
  conv8<32, 16, 33>(bufA, bufB, wf3, w43, sB3, tid);
  __syncthreads();

  // Layer 4: 96 threads, thread -> (oc, one output); softplus on ch1
  if (tid < 96) {
    int oc = tid >= 48;
    int j  = tid - oc * 48;
    int i  = 10 + j;
    float sacc = sB4[oc];
    #pragma unroll
    for (int ic = 0; ic < 16; ++ic) {
      const float* ip = bufB + ic * CSTR + i - 2;
      #pragma unroll
      for (int k = 0; k < 5; ++k)
        sacc = fmaf(ip[k], wt4[oc * 81 + ic * 5 + k], sacc);
    }
    int gp = ts + j;
    if (gp < G) {
      if (oc == 0) {
        yg[(b * 2 + 0) * G + gp] = sacc;
      } else {
        float sp_ = fmaxf(sacc, 0.f) + log1pf(__expf(-fabsf(sacc)));
        yg[(b * 2 + 1) * G + gp] = sp_;
      }
    }
  }
}

// ---------------------------------------------------------------------------
// Kernel C v6: Gaussian recurrence, 2 t per thread, f4 g-PAIR staging
// (halves DS instrs). Block 512 = 8 slices of 128 g x 64 lanes; 64 f4-iters.
// Slices padded to 1024 g; sp zero for g >= 1000 (recurrence values benign).
// ---------------------------------------------------------------------------
__global__ __launch_bounds__(512) void k_pred(
    const float* __restrict__ xt, const float* __restrict__ yt,
    const float* __restrict__ ls_rho, const float* __restrict__ yg,
    float* __restrict__ out) {
  __shared__ float4 sp[512];              // {y0[2j], y1[2j], y0[2j+1], y1[2j+1]}
  __shared__ float pA0[512], pA1[512], pB0[512], pB1[512];
  __shared__ float red[8];

  int tid = threadIdx.x;
  int b = blockIdx.y, tile = blockIdx.x;
  float ls = ls_rho[0];
  float s  = sqrtf(0.5f * LOG2E) / ls;
  float dl = s * (4.4f / 999.f);

  const float* y0 = yg + (b * 2 + 0) * G;
  const float* y1 = yg + (b * 2 + 1) * G;
  {
    int g0 = 2 * tid, g1 = 2 * tid + 1;
    float a0 = (g0 < G) ? y0[g0] : 0.f, b0_ = (g0 < G) ? y1[g0] : 0.f;
    float a1 = (g1 < G) ? y0[g1] : 0.f, b1_ = (g1 < G) ? y1[g1] : 0.f;
    sp[tid] = make_float4(a0, b0_, a1, b1_);
  }
  __syncthreads();

  int lane = tid & 63, wv = tid >> 6;     // wv = g-slice 0..7 (128 g each)
  int ta = tile * 128 + lane;
  float ua = s * xt[b * NT + ta];
  float ub = s * xt[b * NT + ta + 64];
  float base = 2.2f * s - dl * (float)(wv * 128);
  float aa = ua + base, ab = ub + base;
  float Wa = EXP2F(64.f - aa * aa), qa = EXP2F(dl * (aa + aa) - dl * dl);
  float Wb = EXP2F(64.f - ab * ab), qb = EXP2F(dl * (ab + ab) - dl * dl);
  float r  = EXP2F(-2.f * dl * dl);

  float muA = 0.f, sgA = 0.f, muB = 0.f, sgB = 0.f;
  const float4* p = sp + wv * 64;
  #pragma unroll 4
  for (int i = 0; i < 64; ++i) {
    float4 v = p[i];
    muA = fmaf(Wa, v.x, muA); sgA = fmaf(Wa, v.y, sgA); Wa *= qa; qa *= r;
    muB = fmaf(Wb, v.x, muB); sgB = fmaf(Wb, v.y, sgB); Wb *= qb; qb *= r;
    muA = fmaf(Wa, v.z, muA); sgA = fmaf(Wa, v.w, sgA); Wa *= qa; qa *= r;
    muB = fmaf(Wb, v.z, muB); sgB = fmaf(Wb, v.w, sgB); Wb *= qb; qb *= r;
  }
  pA0[tid] = muA; pA1[tid] = sgA; pB0[tid] = muB; pB1[tid] = sgB;
  __syncthreads();

  float lp = 0.f;
  if (tid < 128) {
    int which = tid >> 6, l = tid & 63;
    int t = tile * 128 + which * 64 + l;
    const float* q0 = which ? pB0 : pA0;
    const float* q1 = which ? pB1 : pA1;
    float mu = 0.f, sg = 0.f;
    #pragma unroll
    for (int k = 0; k < 8; ++k) { mu += q0[l + 64 * k]; sg += q1[l + 64 * k]; }
    mu *= 0x1p-64f;
    sg *= 0x1p-64f;
    out[b * NT + t]      = mu;
    out[BN + b * NT + t] = sg;
    float z = (yt[b * NT + t] - mu) / sg;
    lp = -0.5f * z * z - __logf(sg) - 0.5f * LN2PI;
  }
  #pragma unroll
  for (int m = 32; m; m >>= 1) lp += __shfl_xor(lp, m);
  if ((tid & 63) == 0) red[tid >> 6] = lp;
  __syncthreads();
  if (tid == 0) {
    float tot = 0.f;
    #pragma unroll
    for (int i = 0; i < 8; ++i) tot += red[i];
    atomicAdd(out + 2 * BN, -tot * (1.f / (float)NT));
  }
}

extern "C" void kernel_launch(void* const* d_in, const int* in_sizes, int n_in,
                              void* d_out, int out_size, void* d_ws, size_t ws_size,
                              hipStream_t stream) {
  const float* xc  = (const float*)d_in[0];
  const float* yc  = (const float*)d_in[1];
  const float* xt  = (const float*)d_in[2];
  const float* yt  = (const float*)d_in[3];
  const float* lsx = (const float*)d_in[4];
  const float* lsr = (const float*)d_in[5];
  const float* W1  = (const float*)d_in[6];  const float* b1 = (const float*)d_in[7];
  const float* W2  = (const float*)d_in[8];  const float* b2 = (const float*)d_in[9];
  const float* W3  = (const float*)d_in[10]; const float* b3 = (const float*)d_in[11];
  const float* W4  = (const float*)d_in[12]; const float* b4 = (const float*)d_in[13];

  float* out = (float*)d_out;
  float* h   = (float*)d_ws;        // B*2*G
  float* yg  = h + B * 2 * G;       // B*2*G

  k_smooth<<<dim3(8, B), 512, 0, stream>>>(xc, yc, lsx, h, out + 2 * BN);
  k_conv<<<dim3(NTILE, B), 256, 0, stream>>>(h, W1, b1, W2, b2, W3, b3, W4, b4, yg);
  k_pred<<<dim3(16, B), 512, 0, stream>>>(xt, yt, lsr, yg, out);
}

// Round 11
// 42.313 us; speedup vs baseline: 6.8248x; 1.0379x over previous
//
#include <hip/hip_runtime.h>
#include <math.h>

#define G     1000
#define B     32
#define NC    2048
#define NT    2048
#define BN    (B * NT)
#define LOG2E 1.4426950408889634f
#define LN2PI 1.8378770664093453f   // ln(2*pi)

#if __has_builtin(__builtin_amdgcn_exp2f)
#define EXP2F(x) __builtin_amdgcn_exp2f(x)
#else
#define EXP2F(x) exp2f(x)
#endif

// ---------------------------------------------------------------------------
// Kernel A v5: Gaussian recurrence along g. Block 512 = 8 n-slice waves x
// (8 g-runs x 8 n-subs). Lane owns 16 consecutive g + 32 strided n; per n:
// 2 exps + 16x{2 fma, 2 mul} (vs 16 exps). W scaled 2^64 (a^2 <= ~130).
// Strided n per lane -> 8 broadcast groups on 8 distinct banks.
// Grid (8, B) = 256 blocks; tile = 128 g (tile 7 partial).
// ---------------------------------------------------------------------------
__global__ __launch_bounds__(512) void k_smooth(
    const float* __restrict__ xc, const float* __restrict__ yc,
    const float* __restrict__ ls_x, float* __restrict__ h,
    float* __restrict__ loss_slot) {
  __shared__ float2 sxy[NC];              // {s*x_n, y_n}, 16KB
  __shared__ float2 part[8][128];         // per-wave {h0,h1} partials, 8KB
  if (blockIdx.x == 0 && blockIdx.y == 0 && threadIdx.x == 0) *loss_slot = 0.f;

  int tid = threadIdx.x;
  int b = blockIdx.y, tile = blockIdx.x;
  float ls  = ls_x[0];
  float s   = sqrtf(0.5f * LOG2E) / ls;   // w = exp2(-(s*t - s*x)^2)
  float dlt = s * (4.4f / 999.f);

  const float* xb = xc + b * NC;
  const float* yb = yc + b * NC;
  for (int n = tid; n < NC; n += 512) sxy[n] = make_float2(s * xb[n], yb[n]);
  __syncthreads();

  int lane = tid & 63, w = tid >> 6;      // w = n-slice (256 n)
  int ns = lane & 7, gr = lane >> 3;      // 8 n-subs x 8 g-runs
  int g0 = tile * 128 + gr * 16;
  float v0 = s * -2.2f + dlt * (float)g0; // s*t at g0
  float r  = EXP2F(-2.f * dlt * dlt);

  float h0[16], h1[16];
  #pragma unroll
  for (int j = 0; j < 16; ++j) { h0[j] = 0.f; h1[j] = 0.f; }

  const float2* base = sxy + w * 256 + ns;  // lane's n: +8 per step
  #pragma unroll 4
  for (int i = 0; i < 32; ++i) {
    float2 v = base[i * 8];
    float a = v.x - v0;                   // u - v_g0
    float W = EXP2F(64.f - a * a);        // 2^64-scaled first weight
    float q = EXP2F(fmaf(2.f * dlt, a, -dlt * dlt));
    #pragma unroll
    for (int j = 0; j < 16; ++j) {
      h0[j] += W;
      h1[j] = fmaf(W, v.y, h1[j]);
      W *= q; q *= r;
    }
  }
  // reduce over the 8 n-subs (lane bits 0..2)
  #pragma unroll
  for (int m = 1; m < 8; m <<= 1) {
    #pragma unroll
    for (int j = 0; j < 16; ++j) {
      h0[j] += __shfl_xor(h0[j], m);
      h1[j] += __shfl_xor(h1[j], m);
    }
  }
  // lane (gr, ns) stores g-slots ns*2, ns*2+1 of its run
  {
    int j0 = ns * 2;
    part[w][gr * 16 + j0]     = make_float2(h0[j0], h1[j0]);
    part[w][gr * 16 + j0 + 1] = make_float2(h0[j0 + 1], h1[j0 + 1]);
  }
  __syncthreads();

  if (tid < 128) {
    int g = tile * 128 + tid;
    if (g < G) {
      float d0 = 0.f, d1 = 0.f;
      #pragma unroll
      for (int k = 0; k < 8; ++k) { float2 pv = part[k][tid]; d0 += pv.x; d1 += pv.y; }
      d0 *= 0x1p-64f;                     // undo 2^64 scaling
      d1 *= 0x1p-64f;
      h[(b * 2 + 0) * G + g] = d0;
      h[(b * 2 + 1) * G + g] = d1 / (d0 + 1e-8f);
    }
  }
}

// ---------------------------------------------------------------------------
// Kernel B v6 (frozen): POS=8, packed f4 weights. TILE=48, grid (21 x B).
// ---------------------------------------------------------------------------
#define TILE  48
#define NTILE 21   // 21*48 = 1008 >= 1000
#define CSTR  68

template <int CIN, int COUT, int S4>
__device__ __forceinline__ void conv8(
    const float* __restrict__ in, float* __restrict__ out,
    const float4* __restrict__ wf4, const float* __restrict__ w4p,
    const float* __restrict__ bias, int tid) {
  if (tid < COUT * 8) {
    int oc = tid % COUT;
    int i0 = (tid / COUT) * 8;            // reads [i0,i0+12), writes [i0+2,i0+10)
    float acc[8];
    float bb = bias[oc];
    #pragma unroll
    for (int p = 0; p < 8; ++p) acc[p] = bb;
    for (int ic = 0; ic < CIN; ++ic) {
      const float4* ip = (const float4*)(in + ic * CSTR + i0);
      float4 A = ip[0], Bv = ip[1], C = ip[2];
      float v[12] = {A.x, A.y, A.z, A.w, Bv.x, Bv.y, Bv.z, Bv.w, C.x, C.y, C.z, C.w};
      float4 w = wf4[oc * S4 + ic];
      float w4v = w4p[ic * COUT + oc];
      #pragma unroll
      for (int p = 0; p < 8; ++p)
        acc[p] = fmaf(v[p], w.x, fmaf(v[p+1], w.y, fmaf(v[p+2], w.z,
                 fmaf(v[p+3], w.w, fmaf(v[p+4], w4v, acc[p])))));
    }
    float* op = out + oc * CSTR + i0 + 2;
    #pragma unroll
    for (int j = 0; j < 4; ++j)
      *(float2*)(op + 2 * j) = make_float2(fmaxf(acc[2*j], 0.f), fmaxf(acc[2*j+1], 0.f));
  }
}

__global__ __launch_bounds__(256, 2) void k_conv(
    const float* __restrict__ h,
    const float* __restrict__ W1, const float* __restrict__ Bs1,
    const float* __restrict__ W2, const float* __restrict__ Bs2,
    const float* __restrict__ W3, const float* __restrict__ Bs3,
    const float* __restrict__ W4, const float* __restrict__ Bs4,
    float* __restrict__ yg) {
  __shared__ __align__(16) float bufA[32 * CSTR], bufB[32 * CSTR];
  __shared__ float4 wf1[16 * 3], wf2[32 * 17], wf3[16 * 33];
  __shared__ float  w41[2 * 16], w42[16 * 32], w43[32 * 16];
  __shared__ float  wt4[162];
  __shared__ float  sB1[16], sB2[32], sB3[16], sB4[2];

  int tid  = threadIdx.x;
  int tile = blockIdx.x, b = blockIdx.y;
  int ts   = tile * TILE;

  if (tid < 32) {                         // L1: oc<16, ic<2
    int oc = tid >> 1, ic = tid & 1, a = oc * 10 + ic * 5;
    wf1[oc * 3 + ic] = make_float4(W1[a], W1[a+1], W1[a+2], W1[a+3]);
    w41[ic * 16 + oc] = W1[a + 4];
  }
  for (int pr = tid; pr < 512; pr += 256) {   // L2: oc<32, ic<16
    int oc = pr >> 4, ic = pr & 15, a = oc * 80 + ic * 5;
    wf2[oc * 17 + ic] = make_float4(W2[a], W2[a+1], W2[a+2], W2[a+3]);
    w42[ic * 32 + oc] = W2[a + 4];
  }
  for (int pr = tid; pr < 512; pr += 256) {   // L3: oc<16, ic<32
    int oc = pr >> 5, ic = pr & 31, a = oc * 160 + ic * 5;
    wf3[oc * 33 + ic] = make_float4(W3[a], W3[a+1], W3[a+2], W3[a+3]);
    w43[ic * 16 + oc] = W3[a + 4];
  }
  for (int i = tid; i < 160; i += 256) wt4[(i / 80) * 81 + i % 80] = W4[i];
  if (tid < 16)       sB1[tid]      = Bs1[tid];
  else if (tid < 48)  sB2[tid - 16] = Bs2[tid - 16];
  else if (tid < 64)  sB3[tid - 48] = Bs3[tid - 48];
  else if (tid < 66)  sB4[tid - 64] = Bs4[tid - 64];

  for (int i = tid; i < 2 * CSTR; i += 256) {
    int c = i >= CSTR, col = i - c * CSTR;
    int g = ts + col - 10;
    bufA[c * CSTR + col] = (g >= 0 && g < G) ? h[(b * 2 + c) * G + g] : 0.f;
  }
  __syncthreads();

  conv8<2, 16, 3>(bufA, bufB, wf1, w41, sB1, tid);
  __syncthreads();
  conv8<16, 32, 17>(bufB, bufA, wf2, w42, sB2, tid);
  __syncthreads();
  conv8<32, 16, 33>(bufA, bufB, wf3, w43, sB3, tid);
  __syncthreads();

  if (tid < 96) {
    int oc = tid >= 48;
    int j  = tid - oc * 48;
    int i  = 10 + j;
    float sacc = sB4[oc];
    #pragma unroll
    for (int ic = 0; ic < 16; ++ic) {
      const float* ip = bufB + ic * CSTR + i - 2;
      #pragma unroll
      for (int k = 0; k < 5; ++k)
        sacc = fmaf(ip[k], wt4[oc * 81 + ic * 5 + k], sacc);
    }
    int gp = ts + j;
    if (gp < G) {
      if (oc == 0) {
        yg[(b * 2 + 0) * G + gp] = sacc;
      } else {
        float sp_ = fmaxf(sacc, 0.f) + log1pf(__expf(-fabsf(sacc)));
        yg[(b * 2 + 1) * G + gp] = sp_;
      }
    }
  }
}

// ---------------------------------------------------------------------------
// Kernel C v6 (frozen): Gaussian recurrence, 2 t/thread, f4 g-pair staging.
// ---------------------------------------------------------------------------
__global__ __launch_bounds__(512) void k_pred(
    const float* __restrict__ xt, const float* __restrict__ yt,
    const float* __restrict__ ls_rho, const float* __restrict__ yg,
    float* __restrict__ out) {
  __shared__ float4 sp[512];              // {y0[2j], y1[2j], y0[2j+1], y1[2j+1]}
  __shared__ float pA0[512], pA1[512], pB0[512], pB1[512];
  __shared__ float red[8];

  int tid = threadIdx.x;
  int b = blockIdx.y, tile = blockIdx.x;
  float ls = ls_rho[0];
  float s  = sqrtf(0.5f * LOG2E) / ls;
  float dl = s * (4.4f / 999.f);

  const float* y0 = yg + (b * 2 + 0) * G;
  const float* y1 = yg + (b * 2 + 1) * G;
  {
    int g0 = 2 * tid, g1 = 2 * tid + 1;
    float a0 = (g0 < G) ? y0[g0] : 0.f, b0_ = (g0 < G) ? y1[g0] : 0.f;
    float a1 = (g1 < G) ? y0[g1] : 0.f, b1_ = (g1 < G) ? y1[g1] : 0.f;
    sp[tid] = make_float4(a0, b0_, a1, b1_);
  }
  __syncthreads();

  int lane = tid & 63, wv = tid >> 6;     // wv = g-slice 0..7 (128 g each)
  int ta = tile * 128 + lane;
  float ua = s * xt[b * NT + ta];
  float ub = s * xt[b * NT + ta + 64];
  float base = 2.2f * s - dl * (float)(wv * 128);
  float aa = ua + base, ab = ub + base;
  float Wa = EXP2F(64.f - aa * aa), qa = EXP2F(dl * (aa + aa) - dl * dl);
  float Wb = EXP2F(64.f - ab * ab), qb = EXP2F(dl * (ab + ab) - dl * dl);
  float r  = EXP2F(-2.f * dl * dl);

  float muA = 0.f, sgA = 0.f, muB = 0.f, sgB = 0.f;
  const float4* p = sp + wv * 64;
  #pragma unroll 4
  for (int i = 0; i < 64; ++i) {
    float4 v = p[i];
    muA = fmaf(Wa, v.x, muA); sgA = fmaf(Wa, v.y, sgA); Wa *= qa; qa *= r;
    muB = fmaf(Wb, v.x, muB); sgB = fmaf(Wb, v.y, sgB); Wb *= qb; qb *= r;
    muA = fmaf(Wa, v.z, muA); sgA = fmaf(Wa, v.w, sgA); Wa *= qa; qa *= r;
    muB = fmaf(Wb, v.z, muB); sgB = fmaf(Wb, v.w, sgB); Wb *= qb; qb *= r;
  }
  pA0[tid] = muA; pA1[tid] = sgA; pB0[tid] = muB; pB1[tid] = sgB;
  __syncthreads();

  float lp = 0.f;
  if (tid < 128) {
    int which = tid >> 6, l = tid & 63;
    int t = tile * 128 + which * 64 + l;
    const float* q0 = which ? pB0 : pA0;
    const float* q1 = which ? pB1 : pA1;
    float mu = 0.f, sg = 0.f;
    #pragma unroll
    for (int k = 0; k < 8; ++k) { mu += q0[l + 64 * k]; sg += q1[l + 64 * k]; }
    mu *= 0x1p-64f;
    sg *= 0x1p-64f;
    out[b * NT + t]      = mu;
    out[BN + b * NT + t] = sg;
    float z = (yt[b * NT + t] - mu) / sg;
    lp = -0.5f * z * z - __logf(sg) - 0.5f * LN2PI;
  }
  #pragma unroll
  for (int m = 32; m; m >>= 1) lp += __shfl_xor(lp, m);
  if ((tid & 63) == 0) red[tid >> 6] = lp;
  __syncthreads();
  if (tid == 0) {
    float tot = 0.f;
    #pragma unroll
    for (int i = 0; i < 8; ++i) tot += red[i];
    atomicAdd(out + 2 * BN, -tot * (1.f / (float)NT));
  }
}

extern "C" void kernel_launch(void* const* d_in, const int* in_sizes, int n_in,
                              void* d_out, int out_size, void* d_ws, size_t ws_size,
                              hipStream_t stream) {
  const float* xc  = (const float*)d_in[0];
  const float* yc  = (const float*)d_in[1];
  const float* xt  = (const float*)d_in[2];
  const float* yt  = (const float*)d_in[3];
  const float* lsx = (const float*)d_in[4];
  const float* lsr = (const float*)d_in[5];
  const float* W1  = (const float*)d_in[6];  const float* b1 = (const float*)d_in[7];
  const float* W2  = (const float*)d_in[8];  const float* b2 = (const float*)d_in[9];
  const float* W3  = (const float*)d_in[10]; const float* b3 = (const float*)d_in[11];
  const float* W4  = (const float*)d_in[12]; const float* b4 = (const float*)d_in[13];

  float* out = (float*)d_out;
  float* h   = (float*)d_ws;        // B*2*G
  float* yg  = h + B * 2 * G;       // B*2*G

  k_smooth<<<dim3(8, B), 512, 0, stream>>>(xc, yc, lsx, h, out + 2 * BN);
  k_conv<<<dim3(NTILE, B), 256, 0, stream>>>(h, W1, b1, W2, b2, W3, b3, W4, b4, yg);
  k_pred<<<dim3(16, B), 512, 0, stream>>>(xt, yt, lsr, yg, out);
}